// Round 10
// baseline (574.291 us; speedup 1.0000x reference)
//
#include <hip/hip_runtime.h>
#include <hip/hip_bf16.h>

// ScaledDotProductAttention: B=16, N=2048, D=64. q/k/v fp32, mask int32,
// out fp32. scores = q@k^T/sqrt(N); masked -> -1000; softmax over dim=1
// (COLUMN-wise over n); out = attn @ v.
// out[n,d] = sum_m exp(s[n,m])*[!mask] * (v[m,d]/colsum[m]).
//
// R10: NO P materialization (kills the 256 MB pstore round-trip of R6-R9).
// Fused QK^T->exp->PV kernel, viable now that all R2-era pathologies are
// fixed: bitmask (R9, bit-exact), transposed pre-divided vt (R6), bf16 K
// (R3), wave-private LDS relayout + wave_barrier only (R7, bit-identical).
//   1. prep:   pack mask bits (268MB->8MB) + q/k fp32->bf16
//   2. colsum: csp[b][n16][m] partials (MFMA QK^T + bits, LDS-accumulated)
//   3. vprep:  vt[b][d][m] = bf16(v[b][m][d] / colsum[b][m])
//   4. fused:  recompute P tile -> LDS C->A relayout -> PV MFMA; MCH=2
//   5. reduce: sum the 2 partial outputs

#define B_ 16
#define N_ 2048
#define D_ 64
#define SCALE 0.022097086912079608f  // 1/sqrt(2048)
#define MCH 2                        // m-chunks for fused kernel
#define SNCH 4                       // m-chunks for colsum grid.z
#define NWORD (N_ / 32)              // 64 bit-words per mask row

typedef __attribute__((ext_vector_type(8))) short bf16x8;
typedef __attribute__((ext_vector_type(4))) float f32x4;

static __device__ __forceinline__ short f2bf(float x) {
  unsigned u = __float_as_uint(x);
  return (short)((u + 0x7FFF + ((u >> 16) & 1)) >> 16);
}

static __device__ __forceinline__ bf16x8 load8(const short* p) {
  return *reinterpret_cast<const bf16x8*>(p);
}

static __device__ __forceinline__ bf16x8 load8f(const float* p) {
  const f32x4 a = *reinterpret_cast<const f32x4*>(p);
  const f32x4 b = *reinterpret_cast<const f32x4*>(p + 4);
  bf16x8 r;
  r[0] = f2bf(a[0]); r[1] = f2bf(a[1]); r[2] = f2bf(a[2]); r[3] = f2bf(a[3]);
  r[4] = f2bf(b[0]); r[5] = f2bf(b[1]); r[6] = f2bf(b[2]); r[7] = f2bf(b[3]);
  return r;
}

// ---- 1. prep: y==0 pack mask (8192 blocks); y==1 cvt q; y==2 cvt k ----
// bits word w covers mask dwords [w*32, w*32+32); bit = dword_idx % 32.
__global__ __launch_bounds__(256) void prep_kernel(
    const float* __restrict__ q, const float* __restrict__ k,
    const int* __restrict__ mask, short* __restrict__ qb,
    short* __restrict__ kb, unsigned* __restrict__ bits) {
  if (blockIdx.y == 0) {
    const size_t w = (size_t)blockIdx.x * 256 + threadIdx.x;
    const int4* p = reinterpret_cast<const int4*>(mask) + w * 8;
    unsigned r = 0;
#pragma unroll
    for (int j = 0; j < 8; ++j) {
      const int4 x = p[j];
      r |= (x.x ? 1u : 0u) << (j * 4);
      r |= (x.y ? 1u : 0u) << (j * 4 + 1);
      r |= (x.z ? 1u : 0u) << (j * 4 + 2);
      r |= (x.w ? 1u : 0u) << (j * 4 + 3);
    }
    bits[w] = r;
  } else {
    if (blockIdx.x >= (B_ * N_ * D_) / (256 * 8)) return;
    const size_t i = ((size_t)blockIdx.x * 256 + threadIdx.x) * 8;
    const float* src = (blockIdx.y == 2) ? k : q;
    short* dst = (blockIdx.y == 2) ? kb : qb;
    *reinterpret_cast<bf16x8*>(dst + i) = load8f(src + i);
  }
}

// ------- 2. colsum: csp[b][n16][m] = sum over wave's 16 rows of P -------
// grid (B, N/64, SNCH); 4 waves/block; wave owns 16 n-rows, 512 m-cols,
// 64 cols/iteration; colsum accumulated in wave-private LDS, one coalesced
// 512-float store per wave at the end. (R9 score_kernel minus pstore.)
__global__ __launch_bounds__(256) void colsum_kernel(
    const short* __restrict__ qb, const short* __restrict__ kb,
    const unsigned* __restrict__ bits, float* __restrict__ csp) {
  const int b = blockIdx.x;
  const int wave = threadIdx.x >> 6;
  const int lane = threadIdx.x & 63;
  const int l15 = lane & 15;
  const int lhi = lane >> 4;
  const int n0 = blockIdx.y * 64 + wave * 16;
  const int n16 = blockIdx.y * 4 + wave;
  const int mbase = blockIdx.z * (N_ / SNCH);  // 512-wide strip

  const short* qbb = qb + (size_t)b * N_ * D_;
  const short* kbb = kb + (size_t)b * N_ * D_;
  const unsigned* bitsb = bits + (size_t)b * N_ * NWORD;
  float* cspb = csp + ((size_t)b * 128 + n16) * N_;

  const bf16x8 qf0 = load8(qbb + (n0 + l15) * D_ + lhi * 8);
  const bf16x8 qf1 = load8(qbb + (n0 + l15) * D_ + 32 + lhi * 8);

  __shared__ float csl[4][512];  // wave-private colsum accumulator
#pragma unroll
  for (int j = 0; j < 8; ++j) csl[wave][j * 64 + lane] = 0.f;

  for (int m0 = mbase; m0 < mbase + N_ / SNCH; m0 += 64) {
    uint2 w2[4];
#pragma unroll
    for (int r = 0; r < 4; ++r)
      w2[r] = *reinterpret_cast<const uint2*>(
          bitsb + (size_t)(n0 + lhi * 4 + r) * NWORD + (m0 >> 5));
#pragma unroll
    for (int cg = 0; cg < 4; ++cg) {
      const int mc = m0 + cg * 16;
      const bf16x8 kf0 = load8(kbb + (mc + l15) * D_ + lhi * 8);
      const bf16x8 kf1 = load8(kbb + (mc + l15) * D_ + 32 + lhi * 8);
      f32x4 acc = {0.f, 0.f, 0.f, 0.f};
      acc = __builtin_amdgcn_mfma_f32_16x16x32_bf16(qf0, kf0, acc, 0, 0, 0);
      acc = __builtin_amdgcn_mfma_f32_16x16x32_bf16(qf1, kf1, acc, 0, 0, 0);
      float cp = 0.f;
#pragma unroll
      for (int r = 0; r < 4; ++r) {
        const unsigned wsel = (cg < 2) ? w2[r].x : w2[r].y;
        const unsigned bit = (wsel >> ((cg & 1) * 16 + l15)) & 1u;
        cp += bit ? 0.f : __expf(acc[r] * SCALE);
      }
      cp += __shfl_xor(cp, 16, 64);
      cp += __shfl_xor(cp, 32, 64);
      if (lane < 16) csl[wave][m0 - mbase + cg * 16 + l15] += cp;
    }
  }
  __builtin_amdgcn_wave_barrier();
#pragma unroll
  for (int j = 0; j < 2; ++j) {
    f32x4 cv;
#pragma unroll
    for (int e = 0; e < 4; ++e) cv[e] = csl[wave][lane * 8 + j * 4 + e];
    *reinterpret_cast<f32x4*>(cspb + mbase + lane * 8 + j * 4) = cv;
  }
}

// ------- 3. vt[b][d][m] = bf16(v[b][m][d] / sum_{n16} csp[b][n16][m]) -----
__global__ __launch_bounds__(256) void vprep_kernel(
    const float* __restrict__ v, const float* __restrict__ csp,
    short* __restrict__ vt) {
  const int b = blockIdx.x;
  const int m0 = blockIdx.y * 64;
  const int tid = threadIdx.x;
  __shared__ float csl[4][64];
  __shared__ float cst[64];
  __shared__ float lds[64][65];

  {
    const int col = m0 + (tid & 63);
    const int q4 = tid >> 6;
    float s = 0.f;
    for (int j = 0; j < 32; ++j)
      s += csp[((size_t)b * 128 + q4 * 32 + j) * N_ + col];
    csl[q4][tid & 63] = s;
  }
  __syncthreads();
  if (tid < 64) cst[tid] = csl[0][tid] + csl[1][tid] + csl[2][tid] + csl[3][tid];
  __syncthreads();

  const float* vb = v + (size_t)b * N_ * D_;
#pragma unroll
  for (int pass = 0; pass < 4; ++pass) {
    const int mloc = pass * 16 + (tid >> 4);
    const int d4 = (tid & 15) * 4;
    const f32x4 x = *reinterpret_cast<const f32x4*>(vb + (m0 + mloc) * D_ + d4);
    const float ic = 1.0f / cst[mloc];
    lds[mloc][d4 + 0] = x[0] * ic;
    lds[mloc][d4 + 1] = x[1] * ic;
    lds[mloc][d4 + 2] = x[2] * ic;
    lds[mloc][d4 + 3] = x[3] * ic;
  }
  __syncthreads();
  const int d = tid >> 2;
  const int seg = tid & 3;
  bf16x8 o0, o1;
#pragma unroll
  for (int i = 0; i < 8; ++i) o0[i] = f2bf(lds[seg * 16 + i][d]);
#pragma unroll
  for (int i = 0; i < 8; ++i) o1[i] = f2bf(lds[seg * 16 + 8 + i][d]);
  short* dst = vt + (size_t)b * D_ * N_ + (size_t)d * N_ + m0 + seg * 16;
  *reinterpret_cast<bf16x8*>(dst) = o0;
  *reinterpret_cast<bf16x8*>(dst + 8) = o1;
}

// ------- 4. fused: outp[z] = P(:, mchunk z) @ vt(mchunk z, :) -------
// grid (B, N/64, MCH); 4 waves/block; wave owns 16 n-rows, 1024 m-cols,
// 64 cols/iteration. Per iter: 4 uint2 bit loads + 8 K b128 (L2) + 8 QK
// MFMA + exp + wave-private LDS C->A relayout + 8 vt b128 (L2) + 8 PV MFMA.
// No pstore, no block barriers.
__global__ __launch_bounds__(256) void fused_out_kernel(
    const short* __restrict__ qb, const short* __restrict__ kb,
    const short* __restrict__ vt, const unsigned* __restrict__ bits,
    float* __restrict__ outp) {
  const int b = blockIdx.x;
  const int wave = threadIdx.x >> 6;
  const int lane = threadIdx.x & 63;
  const int l15 = lane & 15;
  const int lhi = lane >> 4;
  const int n0 = blockIdx.y * 64 + wave * 16;
  const int mbase = blockIdx.z * (N_ / MCH);  // 1024-wide strip

  const short* qbb = qb + (size_t)b * N_ * D_;
  const short* kbb = kb + (size_t)b * N_ * D_;
  const short* vtb = vt + (size_t)b * D_ * N_;
  const unsigned* bitsb = bits + (size_t)b * N_ * NWORD;

  const bf16x8 qf0 = load8(qbb + (n0 + l15) * D_ + lhi * 8);
  const bf16x8 qf1 = load8(qbb + (n0 + l15) * D_ + 32 + lhi * 8);

  __shared__ __align__(16) short pbuf[4][16][72];  // padded rows

  f32x4 oacc[4];
#pragma unroll
  for (int d = 0; d < 4; ++d) oacc[d] = (f32x4){0.f, 0.f, 0.f, 0.f};

  for (int m0 = mbase; m0 < mbase + N_ / MCH; m0 += 64) {
    uint2 w2[4];
#pragma unroll
    for (int r = 0; r < 4; ++r)
      w2[r] = *reinterpret_cast<const uint2*>(
          bitsb + (size_t)(n0 + lhi * 4 + r) * NWORD + (m0 >> 5));
#pragma unroll
    for (int cg = 0; cg < 4; ++cg) {
      const int mc = m0 + cg * 16;
      const bf16x8 kf0 = load8(kbb + (mc + l15) * D_ + lhi * 8);
      const bf16x8 kf1 = load8(kbb + (mc + l15) * D_ + 32 + lhi * 8);
      f32x4 acc = {0.f, 0.f, 0.f, 0.f};
      acc = __builtin_amdgcn_mfma_f32_16x16x32_bf16(qf0, kf0, acc, 0, 0, 0);
      acc = __builtin_amdgcn_mfma_f32_16x16x32_bf16(qf1, kf1, acc, 0, 0, 0);
#pragma unroll
      for (int r = 0; r < 4; ++r) {
        const unsigned wsel = (cg < 2) ? w2[r].x : w2[r].y;
        const unsigned bit = (wsel >> ((cg & 1) * 16 + l15)) & 1u;
        const float p = bit ? 0.f : __expf(acc[r] * SCALE);
        pbuf[wave][lhi * 4 + r][cg * 16 + l15] = f2bf(p);
      }
    }
    // pbuf is wave-private: DS in-order within a wave; compiler fence only.
    __builtin_amdgcn_wave_barrier();
    // Two 32-col PV A-fragments: A[n=l15][k=lhi*8+j].
    const bf16x8 pa0 =
        *reinterpret_cast<const bf16x8*>(&pbuf[wave][l15][lhi * 8]);
    const bf16x8 pa1 =
        *reinterpret_cast<const bf16x8*>(&pbuf[wave][l15][32 + lhi * 8]);
#pragma unroll
    for (int half = 0; half < 2; ++half) {
      const bf16x8 pa = half ? pa1 : pa0;
      const int mh = m0 + half * 32;
#pragma unroll
      for (int dsub = 0; dsub < 4; ++dsub) {
        const bf16x8 vf =
            load8(vtb + (size_t)(dsub * 16 + l15) * N_ + mh + lhi * 8);
        oacc[dsub] =
            __builtin_amdgcn_mfma_f32_16x16x32_bf16(pa, vf, oacc[dsub], 0, 0, 0);
      }
    }
    __builtin_amdgcn_wave_barrier();  // keep next iter's writes after reads
  }

  float* dst = outp + (size_t)blockIdx.z * B_ * N_ * D_ + (size_t)b * N_ * D_;
#pragma unroll
  for (int dsub = 0; dsub < 4; ++dsub)
#pragma unroll
    for (int r = 0; r < 4; ++r)
      dst[(size_t)(n0 + lhi * 4 + r) * D_ + dsub * 16 + l15] = oacc[dsub][r];
}

// ---------------- 5. reduce the MCH partial outputs ----------------
__global__ __launch_bounds__(256) void reduce_out(const float* __restrict__ outp,
                                                  float* __restrict__ out) {
  const size_t i = ((size_t)blockIdx.x * 256 + threadIdx.x) * 4;
  f32x4 s = *reinterpret_cast<const f32x4*>(outp + i);
#pragma unroll
  for (int z = 1; z < MCH; ++z) {
    const f32x4 x =
        *reinterpret_cast<const f32x4*>(outp + (size_t)z * B_ * N_ * D_ + i);
    s[0] += x[0]; s[1] += x[1]; s[2] += x[2]; s[3] += x[3];
  }
  *reinterpret_cast<f32x4*>(out + i) = s;
}

// ================= R2 fallback (small-workspace path), verified ============
__global__ __launch_bounds__(256) void colsum_fb(
    const float* __restrict__ q, const float* __restrict__ k,
    const int* __restrict__ mask, float* __restrict__ colsum) {
  const int b = blockIdx.x;
  const int wave = threadIdx.x >> 6;
  const int lane = threadIdx.x & 63;
  const int l15 = lane & 15;
  const int lhi = lane >> 4;
  const int m0 = blockIdx.y * 64 + wave * 16;
  const float* qbp = q + (size_t)b * N_ * D_;
  const float* kbp = k + (size_t)b * N_ * D_;
  const int* maskb = mask + (size_t)b * N_ * N_;
  const bf16x8 kf0 = load8f(kbp + (m0 + l15) * D_ + lhi * 8);
  const bf16x8 kf1 = load8f(kbp + (m0 + l15) * D_ + 32 + lhi * 8);
  float partial = 0.f;
  for (int n0 = 0; n0 < N_; n0 += 16) {
    bf16x8 qf0 = load8f(qbp + (n0 + l15) * D_ + lhi * 8);
    bf16x8 qf1 = load8f(qbp + (n0 + l15) * D_ + 32 + lhi * 8);
    f32x4 acc = {0.f, 0.f, 0.f, 0.f};
    acc = __builtin_amdgcn_mfma_f32_16x16x32_bf16(qf0, kf0, acc, 0, 0, 0);
    acc = __builtin_amdgcn_mfma_f32_16x16x32_bf16(qf1, kf1, acc, 0, 0, 0);
#pragma unroll
    for (int r = 0; r < 4; ++r) {
      const int n = n0 + lhi * 4 + r;
      partial +=
          maskb[(size_t)n * N_ + m0 + l15] ? 0.f : __expf(acc[r] * SCALE);
    }
  }
  partial += __shfl_xor(partial, 16, 64);
  partial += __shfl_xor(partial, 32, 64);
  if (lane < 16) colsum[(size_t)b * N_ + m0 + l15] = partial;
}

__global__ __launch_bounds__(256) void attn_out_fb(
    const float* __restrict__ q, const float* __restrict__ k,
    const float* __restrict__ v, const int* __restrict__ mask,
    const float* __restrict__ colsum, float* __restrict__ out) {
  const int b = blockIdx.x;
  const int wave = threadIdx.x >> 6;
  const int lane = threadIdx.x & 63;
  const int l15 = lane & 15;
  const int lhi = lane >> 4;
  const int n0 = blockIdx.y * 64 + wave * 16;
  const float* qbp = q + (size_t)b * N_ * D_;
  const float* kbp = k + (size_t)b * N_ * D_;
  const float* vbp = v + (size_t)b * N_ * D_;
  const int* maskb = mask + (size_t)b * N_ * N_;
  const float* csb = colsum + (size_t)b * N_;
  const bf16x8 qf0 = load8f(qbp + (n0 + l15) * D_ + lhi * 8);
  const bf16x8 qf1 = load8f(qbp + (n0 + l15) * D_ + 32 + lhi * 8);
  __shared__ __align__(16) short pbuf[4][16][32];
  f32x4 oacc[4];
#pragma unroll
  for (int d = 0; d < 4; ++d) oacc[d] = (f32x4){0.f, 0.f, 0.f, 0.f};
  for (int m0 = 0; m0 < N_; m0 += 32) {
#pragma unroll
    for (int cg = 0; cg < 2; ++cg) {
      const int mc = m0 + cg * 16;
      bf16x8 kf0 = load8f(kbp + (mc + l15) * D_ + lhi * 8);
      bf16x8 kf1 = load8f(kbp + (mc + l15) * D_ + 32 + lhi * 8);
      f32x4 acc = {0.f, 0.f, 0.f, 0.f};
      acc = __builtin_amdgcn_mfma_f32_16x16x32_bf16(qf0, kf0, acc, 0, 0, 0);
      acc = __builtin_amdgcn_mfma_f32_16x16x32_bf16(qf1, kf1, acc, 0, 0, 0);
      const float ic = 1.0f / csb[mc + l15];
#pragma unroll
      for (int r = 0; r < 4; ++r) {
        const int n = n0 + lhi * 4 + r;
        const float p = maskb[(size_t)n * N_ + mc + l15]
                            ? 0.f
                            : __expf(acc[r] * SCALE) * ic;
        pbuf[wave][lhi * 4 + r][cg * 16 + l15] = f2bf(p);
      }
    }
    __syncthreads();
    const bf16x8 pa =
        *reinterpret_cast<const bf16x8*>(&pbuf[wave][l15][lhi * 8]);
#pragma unroll
    for (int dsub = 0; dsub < 4; ++dsub) {
      bf16x8 vf;
#pragma unroll
      for (int j = 0; j < 8; ++j)
        vf[j] = f2bf(vbp[(m0 + lhi * 8 + j) * D_ + dsub * 16 + l15]);
      oacc[dsub] =
          __builtin_amdgcn_mfma_f32_16x16x32_bf16(pa, vf, oacc[dsub], 0, 0, 0);
    }
    __syncthreads();
  }
#pragma unroll
  for (int dsub = 0; dsub < 4; ++dsub)
#pragma unroll
    for (int r = 0; r < 4; ++r)
      out[(size_t)b * N_ * D_ + (size_t)(n0 + lhi * 4 + r) * D_ + dsub * 16 +
          l15] = oacc[dsub][r];
}

extern "C" void kernel_launch(void* const* d_in, const int* in_sizes, int n_in,
                              void* d_out, int out_size, void* d_ws,
                              size_t ws_size, hipStream_t stream) {
  const float* q = (const float*)d_in[0];
  const float* k = (const float*)d_in[1];
  const float* v = (const float*)d_in[2];
  const int* mask = (const int*)d_in[3];
  float* out = (float*)d_out;

  // workspace layout (52 MB total)
  const size_t MB = 1024 * 1024;
  const size_t qb_off = 0;                 // 4 MB qbf
  const size_t kb_off = qb_off + 4 * MB;   // 4 MB kbf
  const size_t vt_off = kb_off + 4 * MB;   // 4 MB vt
  const size_t bt_off = vt_off + 4 * MB;   // 8 MB bits
  const size_t cs_off = bt_off + 8 * MB;   // 16 MB csp (128 partials)
  const size_t op_off = cs_off + 16 * MB;  // MCH*8 MB out partials
  const size_t need = op_off + (size_t)MCH * B_ * N_ * D_ * 4;

  if (ws_size >= need) {
    short* qbf = (short*)((char*)d_ws + qb_off);
    short* kbf = (short*)((char*)d_ws + kb_off);
    short* vt = (short*)((char*)d_ws + vt_off);
    unsigned* bits = (unsigned*)((char*)d_ws + bt_off);
    float* csp = (float*)((char*)d_ws + cs_off);
    float* outp = (float*)((char*)d_ws + op_off);

    prep_kernel<<<dim3(8192, 3), 256, 0, stream>>>(q, k, mask, qbf, kbf, bits);
    colsum_kernel<<<dim3(B_, N_ / 64, SNCH), 256, 0, stream>>>(qbf, kbf, bits,
                                                               csp);
    vprep_kernel<<<dim3(B_, N_ / 64), 256, 0, stream>>>(v, csp, vt);
    fused_out_kernel<<<dim3(B_, N_ / 64, MCH), 256, 0, stream>>>(qbf, kbf, vt,
                                                                 bits, outp);
    reduce_out<<<(B_ * N_ * D_) / (256 * 4), 256, 0, stream>>>(outp, out);
  } else {
    float* colsum = (float*)d_ws;  // 128 KB
    colsum_fb<<<dim3(B_, N_ / 64), 256, 0, stream>>>(q, k, mask, colsum);
    attn_out_fb<<<dim3(B_, N_ / 64), 256, 0, stream>>>(q, k, v, mask, colsum,
                                                       out);
  }
}

// Round 11
// 487.751 us; speedup vs baseline: 1.1774x; 1.1774x over previous
//
#include <hip/hip_runtime.h>
#include <hip/hip_bf16.h>

// ScaledDotProductAttention: B=16, N=2048, D=64. q/k/v fp32, mask int32,
// out fp32. scores = q@k^T/sqrt(N); masked -> -1000; softmax over dim=1
// (COLUMN-wise over n); out = attn @ v.
// out[n,d] = sum_m exp(s[n,m])*[!mask] * (v[m,d]/colsum[m]).
//
// R11 = R6/R8 consolidated (R6=497us is the best structure: ONE masked-exp-QK
// pass + streaming PV; R5/R9/R10 proved fusion/bitmask/recompute all lose):
//   - pv: MCH=1, writes d_out directly -> reduce_out dropped (4 dispatches)
//   - score: block-fold colsum at kernel end -> 32 partials (csp 16->4 MB)
//   1. cvt:   q,k fp32 -> bf16
//   2. score: P = exp(S)*!mask (raw mask, read once), stored A-frag-ready
//             + per-block colsum partials
//   3. vprep: vt[b][d][m] = bf16(v[b][m][d] / colsum[b][m])
//   4. pv:    out = P @ vt  — pure streaming MFMA GEMM

#define B_ 16
#define N_ 2048
#define D_ 64
#define SCALE 0.022097086912079608f  // 1/sqrt(2048)
#define SNCH 4                       // m-chunks for score grid.z

typedef __attribute__((ext_vector_type(8))) short bf16x8;
typedef __attribute__((ext_vector_type(4))) float f32x4;

static __device__ __forceinline__ short f2bf(float x) {
  unsigned u = __float_as_uint(x);
  return (short)((u + 0x7FFF + ((u >> 16) & 1)) >> 16);
}

static __device__ __forceinline__ bf16x8 load8(const short* p) {
  return *reinterpret_cast<const bf16x8*>(p);
}

static __device__ __forceinline__ bf16x8 load8f(const float* p) {
  const f32x4 a = *reinterpret_cast<const f32x4*>(p);
  const f32x4 b = *reinterpret_cast<const f32x4*>(p + 4);
  bf16x8 r;
  r[0] = f2bf(a[0]); r[1] = f2bf(a[1]); r[2] = f2bf(a[2]); r[3] = f2bf(a[3]);
  r[4] = f2bf(b[0]); r[5] = f2bf(b[1]); r[6] = f2bf(b[2]); r[7] = f2bf(b[3]);
  return r;
}

// ---------------- 1. fp32 -> bf16 convert (q: y=0, k: y=1) ----------------
__global__ __launch_bounds__(256) void cvt_bf16(const float* __restrict__ q,
                                                const float* __restrict__ k,
                                                short* __restrict__ qb,
                                                short* __restrict__ kb) {
  const size_t i = ((size_t)blockIdx.x * 256 + threadIdx.x) * 8;
  const float* src = blockIdx.y ? k : q;
  short* dst = blockIdx.y ? kb : qb;
  *reinterpret_cast<bf16x8*>(dst + i) = load8f(src + i);
}

// ------- 2. score: P = exp(S)*!mask, stored A-fragment-ready + csp -------
// grid (B, N/64, SNCH); 4 waves/block; wave owns 16 n-rows, 512 m-cols,
// 64 cols/iteration. pstore: [b][n16][mi][lane][8] shorts (mi = m/32) —
// lane's PV A-fragment is one contiguous 16B chunk. Colsum accumulated in
// wave-private LDS, block-folded once at the end:
// csp[b][y][m] = colsum over the block's 64 n-rows (32 partials per (b,m)).
__global__ __launch_bounds__(256) void score_kernel(
    const short* __restrict__ qb, const short* __restrict__ kb,
    const int* __restrict__ mask, short* __restrict__ pstore,
    float* __restrict__ csp) {
  const int b = blockIdx.x;
  const int wave = threadIdx.x >> 6;
  const int lane = threadIdx.x & 63;
  const int l15 = lane & 15;
  const int lhi = lane >> 4;
  const int n0 = blockIdx.y * 64 + wave * 16;
  const int n16 = blockIdx.y * 4 + wave;
  const int mbase = blockIdx.z * (N_ / SNCH);  // 512-wide strip

  const short* qbb = qb + (size_t)b * N_ * D_;
  const short* kbb = kb + (size_t)b * N_ * D_;
  const int* maskb = mask + (size_t)b * N_ * N_;
  short* psb = pstore + (((size_t)b * 128 + n16) * 64) * 512;  // +mi*512

  const bf16x8 qf0 = load8(qbb + (n0 + l15) * D_ + lhi * 8);
  const bf16x8 qf1 = load8(qbb + (n0 + l15) * D_ + 32 + lhi * 8);

  __shared__ __align__(16) short pbuf[4][16][72];  // 2-way-free b128 reads
  __shared__ float csl[4][512];                    // wave-private colsum acc

#pragma unroll
  for (int j = 0; j < 8; ++j) csl[wave][j * 64 + lane] = 0.f;

  for (int m0 = mbase; m0 < mbase + N_ / SNCH; m0 += 64) {
    // All 16 mask words up-front: independent, fill the vmem queue.
    int mk[4][4];
#pragma unroll
    for (int cg = 0; cg < 4; ++cg)
#pragma unroll
      for (int r = 0; r < 4; ++r)
        mk[cg][r] =
            maskb[(size_t)(n0 + lhi * 4 + r) * N_ + m0 + cg * 16 + l15];
#pragma unroll
    for (int cg = 0; cg < 4; ++cg) {
      const int mc = m0 + cg * 16;
      const bf16x8 kf0 = load8(kbb + (mc + l15) * D_ + lhi * 8);
      const bf16x8 kf1 = load8(kbb + (mc + l15) * D_ + 32 + lhi * 8);
      f32x4 acc = {0.f, 0.f, 0.f, 0.f};
      acc = __builtin_amdgcn_mfma_f32_16x16x32_bf16(qf0, kf0, acc, 0, 0, 0);
      acc = __builtin_amdgcn_mfma_f32_16x16x32_bf16(qf1, kf1, acc, 0, 0, 0);
      float cp = 0.f;
#pragma unroll
      for (int r = 0; r < 4; ++r) {
        const float p = mk[cg][r] ? 0.f : __expf(acc[r] * SCALE);
        cp += p;
        pbuf[wave][lhi * 4 + r][cg * 16 + l15] = f2bf(p);
      }
      // lanes {l15,+16,+32,+48} hold partials of the same column.
      cp += __shfl_xor(cp, 16, 64);
      cp += __shfl_xor(cp, 32, 64);
      if (lane < 16) csl[wave][m0 - mbase + cg * 16 + l15] += cp;
    }
    // pbuf/csl are wave-private: DS ops in-order within a wave; compiler
    // fence only — no block barrier, no vmcnt drain.
    __builtin_amdgcn_wave_barrier();
    // A-fragments for the two 32-col units: A[n=l15][k=lhi*8+j].
    const bf16x8 pa0 =
        *reinterpret_cast<const bf16x8*>(&pbuf[wave][l15][lhi * 8]);
    const bf16x8 pa1 =
        *reinterpret_cast<const bf16x8*>(&pbuf[wave][l15][32 + lhi * 8]);
    *reinterpret_cast<bf16x8*>(psb + (size_t)(m0 >> 5) * 512 + lane * 8) = pa0;
    *reinterpret_cast<bf16x8*>(psb + (size_t)((m0 >> 5) + 1) * 512 + lane * 8) =
        pa1;
    __builtin_amdgcn_wave_barrier();  // keep next iter's writes after reads
  }

  // block fold: 4 waves -> one colsum partial for the block's 64 n-rows.
  __syncthreads();
  {
    const int c = threadIdx.x;  // 0..255; handles columns c and c+256
    const float s0 = csl[0][c] + csl[1][c] + csl[2][c] + csl[3][c];
    const float s1 =
        csl[0][c + 256] + csl[1][c + 256] + csl[2][c + 256] + csl[3][c + 256];
    float* dst = csp + ((size_t)b * 32 + blockIdx.y) * N_ + mbase;
    dst[c] = s0;
    dst[c + 256] = s1;
  }
}

// ------- 3. vt[b][d][m] = bf16(v[b][m][d] / sum_{y} csp[b][y][m]) -----
// grid (B, N/64); 64 m-columns per block; folds the 32 partials.
__global__ __launch_bounds__(256) void vprep_kernel(
    const float* __restrict__ v, const float* __restrict__ csp,
    short* __restrict__ vt) {
  const int b = blockIdx.x;
  const int m0 = blockIdx.y * 64;
  const int tid = threadIdx.x;
  __shared__ float csl[4][64];
  __shared__ float cst[64];
  __shared__ float lds[64][65];

  // fold 32 partials: thread t sums 8 of them (quarter t>>6) for col t&63
  {
    const int col = m0 + (tid & 63);
    const int q4 = tid >> 6;
    float s = 0.f;
#pragma unroll
    for (int j = 0; j < 8; ++j)
      s += csp[((size_t)b * 32 + q4 * 8 + j) * N_ + col];
    csl[q4][tid & 63] = s;
  }
  __syncthreads();
  if (tid < 64) cst[tid] = csl[0][tid] + csl[1][tid] + csl[2][tid] + csl[3][tid];
  __syncthreads();

  const float* vb = v + (size_t)b * N_ * D_;
#pragma unroll
  for (int pass = 0; pass < 4; ++pass) {
    const int mloc = pass * 16 + (tid >> 4);
    const int d4 = (tid & 15) * 4;
    const f32x4 x = *reinterpret_cast<const f32x4*>(vb + (m0 + mloc) * D_ + d4);
    const float ic = 1.0f / cst[mloc];
    lds[mloc][d4 + 0] = x[0] * ic;
    lds[mloc][d4 + 1] = x[1] * ic;
    lds[mloc][d4 + 2] = x[2] * ic;
    lds[mloc][d4 + 3] = x[3] * ic;
  }
  __syncthreads();
  const int d = tid >> 2;
  const int seg = tid & 3;
  bf16x8 o0, o1;
#pragma unroll
  for (int i = 0; i < 8; ++i) o0[i] = f2bf(lds[seg * 16 + i][d]);
#pragma unroll
  for (int i = 0; i < 8; ++i) o1[i] = f2bf(lds[seg * 16 + 8 + i][d]);
  short* dst = vt + (size_t)b * D_ * N_ + (size_t)d * N_ + m0 + seg * 16;
  *reinterpret_cast<bf16x8*>(dst) = o0;
  *reinterpret_cast<bf16x8*>(dst + 8) = o1;
}

// ------- 4. pv: out = P @ vt (full m-range, direct output) -------
// grid (B, N/64); pure streaming GEMM: 1 A-frag + 4 B-frag loads + 4 MFMA
// per iter; no LDS, no barriers, no partials.
__global__ __launch_bounds__(256) void pv_kernel(const short* __restrict__ pstore,
                                                 const short* __restrict__ vt,
                                                 float* __restrict__ out) {
  const int b = blockIdx.x;
  const int wave = threadIdx.x >> 6;
  const int lane = threadIdx.x & 63;
  const int l15 = lane & 15;
  const int lhi = lane >> 4;
  const int n0 = blockIdx.y * 64 + wave * 16;
  const int n16 = blockIdx.y * 4 + wave;

  const short* psb =
      pstore + (((size_t)b * 128 + n16) * 64) * 512 + (size_t)lane * 8;
  const short* vtb = vt + (size_t)b * D_ * N_;

  f32x4 oacc[4];
#pragma unroll
  for (int d = 0; d < 4; ++d) oacc[d] = (f32x4){0.f, 0.f, 0.f, 0.f};

#pragma unroll 2
  for (int mi = 0; mi < 64; ++mi) {
    const bf16x8 pa = load8(psb + (size_t)mi * 512);
    const int m0 = mi * 32;
#pragma unroll
    for (int dsub = 0; dsub < 4; ++dsub) {
      const bf16x8 vf =
          load8(vtb + (size_t)(dsub * 16 + l15) * N_ + m0 + lhi * 8);
      oacc[dsub] =
          __builtin_amdgcn_mfma_f32_16x16x32_bf16(pa, vf, oacc[dsub], 0, 0, 0);
    }
  }

  float* dst = out + (size_t)b * N_ * D_;
#pragma unroll
  for (int dsub = 0; dsub < 4; ++dsub)
#pragma unroll
    for (int r = 0; r < 4; ++r)
      dst[(size_t)(n0 + lhi * 4 + r) * D_ + dsub * 16 + l15] = oacc[dsub][r];
}

// ================= R2 fallback (small-workspace path), verified ============
__global__ __launch_bounds__(256) void colsum_fb(
    const float* __restrict__ q, const float* __restrict__ k,
    const int* __restrict__ mask, float* __restrict__ colsum) {
  const int b = blockIdx.x;
  const int wave = threadIdx.x >> 6;
  const int lane = threadIdx.x & 63;
  const int l15 = lane & 15;
  const int lhi = lane >> 4;
  const int m0 = blockIdx.y * 64 + wave * 16;
  const float* qbp = q + (size_t)b * N_ * D_;
  const float* kbp = k + (size_t)b * N_ * D_;
  const int* maskb = mask + (size_t)b * N_ * N_;
  const bf16x8 kf0 = load8f(kbp + (m0 + l15) * D_ + lhi * 8);
  const bf16x8 kf1 = load8f(kbp + (m0 + l15) * D_ + 32 + lhi * 8);
  float partial = 0.f;
  for (int n0 = 0; n0 < N_; n0 += 16) {
    bf16x8 qf0 = load8f(qbp + (n0 + l15) * D_ + lhi * 8);
    bf16x8 qf1 = load8f(qbp + (n0 + l15) * D_ + 32 + lhi * 8);
    f32x4 acc = {0.f, 0.f, 0.f, 0.f};
    acc = __builtin_amdgcn_mfma_f32_16x16x32_bf16(qf0, kf0, acc, 0, 0, 0);
    acc = __builtin_amdgcn_mfma_f32_16x16x32_bf16(qf1, kf1, acc, 0, 0, 0);
#pragma unroll
    for (int r = 0; r < 4; ++r) {
      const int n = n0 + lhi * 4 + r;
      partial +=
          maskb[(size_t)n * N_ + m0 + l15] ? 0.f : __expf(acc[r] * SCALE);
    }
  }
  partial += __shfl_xor(partial, 16, 64);
  partial += __shfl_xor(partial, 32, 64);
  if (lane < 16) colsum[(size_t)b * N_ + m0 + l15] = partial;
}

__global__ __launch_bounds__(256) void attn_out_fb(
    const float* __restrict__ q, const float* __restrict__ k,
    const float* __restrict__ v, const int* __restrict__ mask,
    const float* __restrict__ colsum, float* __restrict__ out) {
  const int b = blockIdx.x;
  const int wave = threadIdx.x >> 6;
  const int lane = threadIdx.x & 63;
  const int l15 = lane & 15;
  const int lhi = lane >> 4;
  const int n0 = blockIdx.y * 64 + wave * 16;
  const float* qbp = q + (size_t)b * N_ * D_;
  const float* kbp = k + (size_t)b * N_ * D_;
  const float* vbp = v + (size_t)b * N_ * D_;
  const int* maskb = mask + (size_t)b * N_ * N_;
  const float* csb = colsum + (size_t)b * N_;
  const bf16x8 qf0 = load8f(qbp + (n0 + l15) * D_ + lhi * 8);
  const bf16x8 qf1 = load8f(qbp + (n0 + l15) * D_ + 32 + lhi * 8);
  __shared__ __align__(16) short pbuf[4][16][32];
  f32x4 oacc[4];
#pragma unroll
  for (int d = 0; d < 4; ++d) oacc[d] = (f32x4){0.f, 0.f, 0.f, 0.f};
  for (int m0 = 0; m0 < N_; m0 += 32) {
#pragma unroll
    for (int cg = 0; cg < 2; ++cg) {
      const int mc = m0 + cg * 16;
      bf16x8 kf0 = load8f(kbp + (mc + l15) * D_ + lhi * 8);
      bf16x8 kf1 = load8f(kbp + (mc + l15) * D_ + 32 + lhi * 8);
      f32x4 acc = {0.f, 0.f, 0.f, 0.f};
      acc = __builtin_amdgcn_mfma_f32_16x16x32_bf16(qf0, kf0, acc, 0, 0, 0);
      acc = __builtin_amdgcn_mfma_f32_16x16x32_bf16(qf1, kf1, acc, 0, 0, 0);
      const float ic = 1.0f / csb[mc + l15];
#pragma unroll
      for (int r = 0; r < 4; ++r) {
        const int n = n0 + lhi * 4 + r;
        const float p = maskb[(size_t)n * N_ + mc + l15]
                            ? 0.f
                            : __expf(acc[r] * SCALE) * ic;
        pbuf[wave][lhi * 4 + r][cg * 16 + l15] = f2bf(p);
      }
    }
    __syncthreads();
    const bf16x8 pa =
        *reinterpret_cast<const bf16x8*>(&pbuf[wave][l15][lhi * 8]);
#pragma unroll
    for (int dsub = 0; dsub < 4; ++dsub) {
      bf16x8 vf;
#pragma unroll
      for (int j = 0; j < 8; ++j)
        vf[j] = f2bf(vbp[(m0 + lhi * 8 + j) * D_ + dsub * 16 + l15]);
      oacc[dsub] =
          __builtin_amdgcn_mfma_f32_16x16x32_bf16(pa, vf, oacc[dsub], 0, 0, 0);
    }
    __syncthreads();
  }
#pragma unroll
  for (int dsub = 0; dsub < 4; ++dsub)
#pragma unroll
    for (int r = 0; r < 4; ++r)
      out[(size_t)b * N_ * D_ + (size_t)(n0 + lhi * 4 + r) * D_ + dsub * 16 +
          l15] = oacc[dsub][r];
}

extern "C" void kernel_launch(void* const* d_in, const int* in_sizes, int n_in,
                              void* d_out, int out_size, void* d_ws,
                              size_t ws_size, hipStream_t stream) {
  const float* q = (const float*)d_in[0];
  const float* k = (const float*)d_in[1];
  const float* v = (const float*)d_in[2];
  const int* mask = (const int*)d_in[3];
  float* out = (float*)d_out;

  // workspace layout (144 MB total)
  const size_t MB = 1024 * 1024;
  const size_t qb_off = 0;                // 4 MB qbf
  const size_t kb_off = qb_off + 4 * MB;  // 4 MB kbf
  const size_t vt_off = kb_off + 4 * MB;  // 4 MB vt
  const size_t cs_off = vt_off + 4 * MB;  // 4 MB csp (32 partials)
  const size_t ps_off = cs_off + 4 * MB;  // 128 MB pstore
  const size_t need = ps_off + 128 * MB;

  if (ws_size >= need) {
    short* qbf = (short*)((char*)d_ws + qb_off);
    short* kbf = (short*)((char*)d_ws + kb_off);
    short* vt = (short*)((char*)d_ws + vt_off);
    float* csp = (float*)((char*)d_ws + cs_off);
    short* pstore = (short*)((char*)d_ws + ps_off);

    cvt_bf16<<<dim3((B_ * N_ * D_) / (256 * 8), 2), 256, 0, stream>>>(
        q, k, qbf, kbf);
    score_kernel<<<dim3(B_, N_ / 64, SNCH), 256, 0, stream>>>(qbf, kbf, mask,
                                                              pstore, csp);
    vprep_kernel<<<dim3(B_, N_ / 64), 256, 0, stream>>>(v, csp, vt);
    pv_kernel<<<dim3(B_, N_ / 64), 256, 0, stream>>>(pstore, vt, out);
  } else {
    float* colsum = (float*)d_ws;  // 128 KB
    colsum_fb<<<dim3(B_, N_ / 64), 256, 0, stream>>>(q, k, mask, colsum);
    attn_out_fb<<<dim3(B_, N_ / 64), 256, 0, stream>>>(q, k, v, mask, colsum,
                                                       out);
  }
}

// Round 12
// 462.422 us; speedup vs baseline: 1.2419x; 1.0548x over previous
//
#include <hip/hip_runtime.h>
#include <hip/hip_bf16.h>

// ScaledDotProductAttention: B=16, N=2048, D=64. q/k/v fp32, mask int32,
// out fp32. scores = q@k^T/sqrt(N); masked -> -1000; softmax over dim=1
// (COLUMN-wise over n); out = attn @ v.
// out[n,d] = sum_m exp(s[n,m])*[!mask] * (v[m,d]/colsum[m]).
//
// R12 = R11 with score_kernel re-oriented M-MAJOR (wave owns 32 m-cols,
// iterates n). Wins vs R11's n-major loop:
//   - K-fragments loop-invariant -> hoisted (were 8 b128 reloads/iter)
//   - colsum accumulates in 2 REGISTERS (was 8 ds_swizzle + 4 exec-masked
//     LDS RMW per iter — serialized ~120cyc DS chains); folded once at end
//   - inner loop: 8 mask dwords + 2 Q b128 + 4 MFMA + 8 exp + 8 ds_write_b16
//     + 1 ds_read_b128 + 1 16B pstore. No csl LDS at all.
// Pipeline (4 dispatches): cvt -> score -> vprep -> pv(direct out).

#define B_ 16
#define N_ 2048
#define D_ 64
#define SCALE 0.022097086912079608f  // 1/sqrt(2048)
#define NCH 8                        // n-chunks for score grid.z

typedef __attribute__((ext_vector_type(8))) short bf16x8;
typedef __attribute__((ext_vector_type(4))) float f32x4;

static __device__ __forceinline__ short f2bf(float x) {
  unsigned u = __float_as_uint(x);
  return (short)((u + 0x7FFF + ((u >> 16) & 1)) >> 16);
}

static __device__ __forceinline__ bf16x8 load8(const short* p) {
  return *reinterpret_cast<const bf16x8*>(p);
}

static __device__ __forceinline__ bf16x8 load8f(const float* p) {
  const f32x4 a = *reinterpret_cast<const f32x4*>(p);
  const f32x4 b = *reinterpret_cast<const f32x4*>(p + 4);
  bf16x8 r;
  r[0] = f2bf(a[0]); r[1] = f2bf(a[1]); r[2] = f2bf(a[2]); r[3] = f2bf(a[3]);
  r[4] = f2bf(b[0]); r[5] = f2bf(b[1]); r[6] = f2bf(b[2]); r[7] = f2bf(b[3]);
  return r;
}

// ---------------- 1. fp32 -> bf16 convert (q: y=0, k: y=1) ----------------
__global__ __launch_bounds__(256) void cvt_bf16(const float* __restrict__ q,
                                                const float* __restrict__ k,
                                                short* __restrict__ qb,
                                                short* __restrict__ kb) {
  const size_t i = ((size_t)blockIdx.x * 256 + threadIdx.x) * 8;
  const float* src = blockIdx.y ? k : q;
  short* dst = blockIdx.y ? kb : qb;
  *reinterpret_cast<bf16x8*>(dst + i) = load8f(src + i);
}

// ------- 2. score (m-major): P = exp(S)*!mask, A-frag-ready + csp -------
// grid (B, N/128, NCH); 4 waves/block; wave owns 32 m-cols (m0 = y*128 +
// wave*32), iterates its 256-row n-chunk in 16-row tiles (16 iters).
// pstore: [b][n16][mi][lane][8] shorts (n16 = n/16, mi = m/32) — lane's PV
// A-fragment is one contiguous 16B chunk; block writes 4KB contig per iter.
// csp[b][z][m]: colsum partial over chunk z's 256 rows (register-held).
__global__ __launch_bounds__(256) void score_kernel(
    const short* __restrict__ qb, const short* __restrict__ kb,
    const int* __restrict__ mask, short* __restrict__ pstore,
    float* __restrict__ csp) {
  const int b = blockIdx.x;
  const int wave = threadIdx.x >> 6;
  const int lane = threadIdx.x & 63;
  const int l15 = lane & 15;
  const int lhi = lane >> 4;
  const int m0 = blockIdx.y * 128 + wave * 32;
  const int mi = m0 >> 5;
  const int nbase = blockIdx.z * (N_ / NCH);  // 256-row chunk

  const short* qbb = qb + (size_t)b * N_ * D_;
  const short* kbb = kb + (size_t)b * N_ * D_;
  const int* maskb = mask + (size_t)b * N_ * N_;

  // K-fragments: loop-invariant (m fixed per wave) — loaded ONCE.
  bf16x8 kf[2][2];
#pragma unroll
  for (int cg = 0; cg < 2; ++cg) {
    kf[cg][0] = load8(kbb + (m0 + cg * 16 + l15) * D_ + lhi * 8);
    kf[cg][1] = load8(kbb + (m0 + cg * 16 + l15) * D_ + 32 + lhi * 8);
  }

  __shared__ __align__(16) short pbuf[4][16][40];  // stride 80B: 2-way-free

  float cs0 = 0.f, cs1 = 0.f;  // register colsum partials (cols m0+cg*16+l15)

  for (int n0 = nbase; n0 < nbase + N_ / NCH; n0 += 16) {
    // independent mask words up-front (fill vmem queue)
    int mk[2][4];
#pragma unroll
    for (int cg = 0; cg < 2; ++cg)
#pragma unroll
      for (int r = 0; r < 4; ++r)
        mk[cg][r] =
            maskb[(size_t)(n0 + lhi * 4 + r) * N_ + m0 + cg * 16 + l15];
    // Q A-fragments for this n-tile
    const bf16x8 qf0 = load8(qbb + (n0 + l15) * D_ + lhi * 8);
    const bf16x8 qf1 = load8(qbb + (n0 + l15) * D_ + 32 + lhi * 8);
#pragma unroll
    for (int cg = 0; cg < 2; ++cg) {
      f32x4 acc = {0.f, 0.f, 0.f, 0.f};
      acc = __builtin_amdgcn_mfma_f32_16x16x32_bf16(qf0, kf[cg][0], acc, 0, 0, 0);
      acc = __builtin_amdgcn_mfma_f32_16x16x32_bf16(qf1, kf[cg][1], acc, 0, 0, 0);
      float cp = 0.f;
#pragma unroll
      for (int r = 0; r < 4; ++r) {
        // C-layout: row n = n0+lhi*4+r, col m = m0+cg*16+l15
        const float p = mk[cg][r] ? 0.f : __expf(acc[r] * SCALE);
        cp += p;
        pbuf[wave][lhi * 4 + r][cg * 16 + l15] = f2bf(p);
      }
      if (cg == 0) cs0 += cp; else cs1 += cp;
    }
    // pbuf is wave-private: DS in-order within a wave; compiler fence only.
    __builtin_amdgcn_wave_barrier();
    // PV A-fragment unit (16n x 32m): A[n=l15][k=lhi*8+j], one b128.
    const bf16x8 pa =
        *reinterpret_cast<const bf16x8*>(&pbuf[wave][l15][lhi * 8]);
    const int n16 = n0 >> 4;
    *reinterpret_cast<bf16x8*>(
        pstore + (((size_t)b * 128 + n16) * 64 + mi) * 512 + lane * 8) = pa;
    __builtin_amdgcn_wave_barrier();  // keep next iter's writes after read
  }

  // fold colsum across the 4 row-groups (lanes xor 16, 32), store once.
  cs0 += __shfl_xor(cs0, 16, 64);
  cs0 += __shfl_xor(cs0, 32, 64);
  cs1 += __shfl_xor(cs1, 16, 64);
  cs1 += __shfl_xor(cs1, 32, 64);
  float* cspz = csp + ((size_t)b * NCH + blockIdx.z) * N_;
  if (lane < 16) {
    cspz[m0 + l15] = cs0;
    cspz[m0 + 16 + l15] = cs1;
  }
}

// ------- 3. vt[b][d][m] = bf16(v[b][m][d] / sum_z csp[b][z][m]) -----
// grid (B, N/64); 64 m-columns per block; folds the 8 partials.
__global__ __launch_bounds__(256) void vprep_kernel(
    const float* __restrict__ v, const float* __restrict__ csp,
    short* __restrict__ vt) {
  const int b = blockIdx.x;
  const int m0 = blockIdx.y * 64;
  const int tid = threadIdx.x;
  __shared__ float csl[4][64];
  __shared__ float cst[64];
  __shared__ float lds[64][65];

  // fold 8 partials: quarter q4 = tid>>6 sums 2 of them for col tid&63
  {
    const int col = m0 + (tid & 63);
    const int q4 = tid >> 6;
    float s = 0.f;
#pragma unroll
    for (int j = 0; j < 2; ++j)
      s += csp[((size_t)b * NCH + q4 * 2 + j) * N_ + col];
    csl[q4][tid & 63] = s;
  }
  __syncthreads();
  if (tid < 64) cst[tid] = csl[0][tid] + csl[1][tid] + csl[2][tid] + csl[3][tid];
  __syncthreads();

  const float* vb = v + (size_t)b * N_ * D_;
#pragma unroll
  for (int pass = 0; pass < 4; ++pass) {
    const int mloc = pass * 16 + (tid >> 4);
    const int d4 = (tid & 15) * 4;
    const f32x4 x = *reinterpret_cast<const f32x4*>(vb + (m0 + mloc) * D_ + d4);
    const float ic = 1.0f / cst[mloc];
    lds[mloc][d4 + 0] = x[0] * ic;
    lds[mloc][d4 + 1] = x[1] * ic;
    lds[mloc][d4 + 2] = x[2] * ic;
    lds[mloc][d4 + 3] = x[3] * ic;
  }
  __syncthreads();
  const int d = tid >> 2;
  const int seg = tid & 3;
  bf16x8 o0, o1;
#pragma unroll
  for (int i = 0; i < 8; ++i) o0[i] = f2bf(lds[seg * 16 + i][d]);
#pragma unroll
  for (int i = 0; i < 8; ++i) o1[i] = f2bf(lds[seg * 16 + 8 + i][d]);
  short* dst = vt + (size_t)b * D_ * N_ + (size_t)d * N_ + m0 + seg * 16;
  *reinterpret_cast<bf16x8*>(dst) = o0;
  *reinterpret_cast<bf16x8*>(dst + 8) = o1;
}

// ------- 4. pv: out = P @ vt (full m-range, direct output) -------
// grid (B, N/64); pure streaming GEMM: 1 A-frag + 4 B-frag loads + 4 MFMA
// per iter; no LDS, no barriers, no partials.
__global__ __launch_bounds__(256) void pv_kernel(const short* __restrict__ pstore,
                                                 const short* __restrict__ vt,
                                                 float* __restrict__ out) {
  const int b = blockIdx.x;
  const int wave = threadIdx.x >> 6;
  const int lane = threadIdx.x & 63;
  const int l15 = lane & 15;
  const int lhi = lane >> 4;
  const int n0 = blockIdx.y * 64 + wave * 16;
  const int n16 = blockIdx.y * 4 + wave;

  const short* psb =
      pstore + (((size_t)b * 128 + n16) * 64) * 512 + (size_t)lane * 8;
  const short* vtb = vt + (size_t)b * D_ * N_;

  f32x4 oacc[4];
#pragma unroll
  for (int d = 0; d < 4; ++d) oacc[d] = (f32x4){0.f, 0.f, 0.f, 0.f};

#pragma unroll 2
  for (int mi = 0; mi < 64; ++mi) {
    const bf16x8 pa = load8(psb + (size_t)mi * 512);
    const int m0 = mi * 32;
#pragma unroll
    for (int dsub = 0; dsub < 4; ++dsub) {
      const bf16x8 vf =
          load8(vtb + (size_t)(dsub * 16 + l15) * N_ + m0 + lhi * 8);
      oacc[dsub] =
          __builtin_amdgcn_mfma_f32_16x16x32_bf16(pa, vf, oacc[dsub], 0, 0, 0);
    }
  }

  float* dst = out + (size_t)b * N_ * D_;
#pragma unroll
  for (int dsub = 0; dsub < 4; ++dsub)
#pragma unroll
    for (int r = 0; r < 4; ++r)
      dst[(size_t)(n0 + lhi * 4 + r) * D_ + dsub * 16 + l15] = oacc[dsub][r];
}

// ================= R2 fallback (small-workspace path), verified ============
__global__ __launch_bounds__(256) void colsum_fb(
    const float* __restrict__ q, const float* __restrict__ k,
    const int* __restrict__ mask, float* __restrict__ colsum) {
  const int b = blockIdx.x;
  const int wave = threadIdx.x >> 6;
  const int lane = threadIdx.x & 63;
  const int l15 = lane & 15;
  const int lhi = lane >> 4;
  const int m0 = blockIdx.y * 64 + wave * 16;
  const float* qbp = q + (size_t)b * N_ * D_;
  const float* kbp = k + (size_t)b * N_ * D_;
  const int* maskb = mask + (size_t)b * N_ * N_;
  const bf16x8 kf0 = load8f(kbp + (m0 + l15) * D_ + lhi * 8);
  const bf16x8 kf1 = load8f(kbp + (m0 + l15) * D_ + 32 + lhi * 8);
  float partial = 0.f;
  for (int n0 = 0; n0 < N_; n0 += 16) {
    bf16x8 qf0 = load8f(qbp + (n0 + l15) * D_ + lhi * 8);
    bf16x8 qf1 = load8f(qbp + (n0 + l15) * D_ + 32 + lhi * 8);
    f32x4 acc = {0.f, 0.f, 0.f, 0.f};
    acc = __builtin_amdgcn_mfma_f32_16x16x32_bf16(qf0, kf0, acc, 0, 0, 0);
    acc = __builtin_amdgcn_mfma_f32_16x16x32_bf16(qf1, kf1, acc, 0, 0, 0);
#pragma unroll
    for (int r = 0; r < 4; ++r) {
      const int n = n0 + lhi * 4 + r;
      partial +=
          maskb[(size_t)n * N_ + m0 + l15] ? 0.f : __expf(acc[r] * SCALE);
    }
  }
  partial += __shfl_xor(partial, 16, 64);
  partial += __shfl_xor(partial, 32, 64);
  if (lane < 16) colsum[(size_t)b * N_ + m0 + l15] = partial;
}

__global__ __launch_bounds__(256) void attn_out_fb(
    const float* __restrict__ q, const float* __restrict__ k,
    const float* __restrict__ v, const int* __restrict__ mask,
    const float* __restrict__ colsum, float* __restrict__ out) {
  const int b = blockIdx.x;
  const int wave = threadIdx.x >> 6;
  const int lane = threadIdx.x & 63;
  const int l15 = lane & 15;
  const int lhi = lane >> 4;
  const int n0 = blockIdx.y * 64 + wave * 16;
  const float* qbp = q + (size_t)b * N_ * D_;
  const float* kbp = k + (size_t)b * N_ * D_;
  const float* vbp = v + (size_t)b * N_ * D_;
  const int* maskb = mask + (size_t)b * N_ * N_;
  const float* csb = colsum + (size_t)b * N_;
  const bf16x8 qf0 = load8f(qbp + (n0 + l15) * D_ + lhi * 8);
  const bf16x8 qf1 = load8f(qbp + (n0 + l15) * D_ + 32 + lhi * 8);
  __shared__ __align__(16) short pbuf[4][16][32];
  f32x4 oacc[4];
#pragma unroll
  for (int d = 0; d < 4; ++d) oacc[d] = (f32x4){0.f, 0.f, 0.f, 0.f};
  for (int m0 = 0; m0 < N_; m0 += 32) {
#pragma unroll
    for (int cg = 0; cg < 2; ++cg) {
      const int mc = m0 + cg * 16;
      bf16x8 kf0 = load8f(kbp + (mc + l15) * D_ + lhi * 8);
      bf16x8 kf1 = load8f(kbp + (mc + l15) * D_ + 32 + lhi * 8);
      f32x4 acc = {0.f, 0.f, 0.f, 0.f};
      acc = __builtin_amdgcn_mfma_f32_16x16x32_bf16(qf0, kf0, acc, 0, 0, 0);
      acc = __builtin_amdgcn_mfma_f32_16x16x32_bf16(qf1, kf1, acc, 0, 0, 0);
      const float ic = 1.0f / csb[mc + l15];
#pragma unroll
      for (int r = 0; r < 4; ++r) {
        const int n = n0 + lhi * 4 + r;
        const float p = maskb[(size_t)n * N_ + mc + l15]
                            ? 0.f
                            : __expf(acc[r] * SCALE) * ic;
        pbuf[wave][lhi * 4 + r][cg * 16 + l15] = f2bf(p);
      }
    }
    __syncthreads();
    const bf16x8 pa =
        *reinterpret_cast<const bf16x8*>(&pbuf[wave][l15][lhi * 8]);
#pragma unroll
    for (int dsub = 0; dsub < 4; ++dsub) {
      bf16x8 vf;
#pragma unroll
      for (int j = 0; j < 8; ++j)
        vf[j] = f2bf(vbp[(m0 + lhi * 8 + j) * D_ + dsub * 16 + l15]);
      oacc[dsub] =
          __builtin_amdgcn_mfma_f32_16x16x32_bf16(pa, vf, oacc[dsub], 0, 0, 0);
    }
    __syncthreads();
  }
#pragma unroll
  for (int dsub = 0; dsub < 4; ++dsub)
#pragma unroll
    for (int r = 0; r < 4; ++r)
      out[(size_t)b * N_ * D_ + (size_t)(n0 + lhi * 4 + r) * D_ + dsub * 16 +
          l15] = oacc[dsub][r];
}

extern "C" void kernel_launch(void* const* d_in, const int* in_sizes, int n_in,
                              void* d_out, int out_size, void* d_ws,
                              size_t ws_size, hipStream_t stream) {
  const float* q = (const float*)d_in[0];
  const float* k = (const float*)d_in[1];
  const float* v = (const float*)d_in[2];
  const int* mask = (const int*)d_in[3];
  float* out = (float*)d_out;

  // workspace layout (~141 MB total)
  const size_t MB = 1024 * 1024;
  const size_t qb_off = 0;                // 4 MB qbf
  const size_t kb_off = qb_off + 4 * MB;  // 4 MB kbf
  const size_t vt_off = kb_off + 4 * MB;  // 4 MB vt
  const size_t cs_off = vt_off + 4 * MB;  // 1 MB csp (8 partials)
  const size_t ps_off = cs_off + 1 * MB;  // 128 MB pstore
  const size_t need = ps_off + 128 * MB;

  if (ws_size >= need) {
    short* qbf = (short*)((char*)d_ws + qb_off);
    short* kbf = (short*)((char*)d_ws + kb_off);
    short* vt = (short*)((char*)d_ws + vt_off);
    float* csp = (float*)((char*)d_ws + cs_off);
    short* pstore = (short*)((char*)d_ws + ps_off);

    cvt_bf16<<<dim3((B_ * N_ * D_) / (256 * 8), 2), 256, 0, stream>>>(
        q, k, qbf, kbf);
    score_kernel<<<dim3(B_, N_ / 128, NCH), 256, 0, stream>>>(qbf, kbf, mask,
                                                              pstore, csp);
    vprep_kernel<<<dim3(B_, N_ / 64), 256, 0, stream>>>(v, csp, vt);
    pv_kernel<<<dim3(B_, N_ / 64), 256, 0, stream>>>(pstore, vt, out);
  } else {
    float* colsum = (float*)d_ws;  // 128 KB
    colsum_fb<<<dim3(B_, N_ / 64), 256, 0, stream>>>(q, k, mask, colsum);
    attn_out_fb<<<dim3(B_, N_ / 64), 256, 0, stream>>>(q, k, v, mask, colsum,
                                                       out);
  }
}